// Round 3
// baseline (371.538 us; speedup 1.0000x reference)
//
#include <hip/hip_runtime.h>
#include <math.h>

#define BB 4096
#define TT 200
#define NT (BB*TT)

// ---- prep per-b: WBtab[b] = Wa + Wc + ie_b (x) Wd   ([64][36], row k major)
//                  TBuf[b]  = ie_b @ (Wb - Wc) + au_b1
__global__ __launch_bounds__(256) void k_prep(const int* __restrict__ item,
                                              const float* __restrict__ Itab,
                                              const float* __restrict__ auW1,
                                              const float* __restrict__ auB1,
                                              float* __restrict__ WBtab,
                                              float* __restrict__ TBuf) {
  int b = blockIdx.x, tid = threadIdx.x;
  __shared__ float sIe[64];
  if (tid < 64) sIe[tid] = Itab[(size_t)item[b] * 64 + tid];
  __syncthreads();
  const float* Wa = auW1;
  const float* Wbm = auW1 + 64 * 36;
  const float* Wc = auW1 + 128 * 36;
  const float* Wd = auW1 + 192 * 36;
  float* wb = WBtab + (size_t)b * 2304;
  for (int i = tid; i < 2304; i += 256) {
    int k = i / 36;
    wb[i] = Wa[i] + Wc[i] + sIe[k] * Wd[i];
  }
  if (tid < 36) {
    float a = auB1[tid];
    for (int k = 0; k < 64; ++k)
      a += sIe[k] * (Wbm[k * 36 + tid] - Wc[k * 36 + tid]);
    TBuf[b * 36 + tid] = a;
  }
}

// ---- core matvec with wave-uniform (scalar-pipe) weights.
// PASS 1: per-b stats partials.   PASS 2: dice + attention weight.
template<int PASS>
__global__ __launch_bounds__(256) void k_core_sg(
    const int* __restrict__ hist,
    const float* __restrict__ Itab,
    const float* __restrict__ WBtab,
    const float* __restrict__ TBuf,
    const float* __restrict__ AUST,
    const float* __restrict__ auA1,
    const float* __restrict__ auW2,
    const float* __restrict__ auB2,
    float* __restrict__ PART,
    float* __restrict__ Wbuf) {
  const int b = blockIdx.x, tid = threadIdx.x;
  const float* __restrict__ wb = WBtab + (size_t)b * 2304;  // wave-uniform
  const bool act = tid < TT;
  float acc[36];
  {
    const float* tb = TBuf + b * 36;  // uniform
#pragma unroll
    for (int j = 0; j < 36; ++j) acc[j] = tb[j];
  }
  if (act) {
    const int row = hist[b * TT + tid];
    const float4* __restrict__ rp4 = (const float4*)(Itab + (size_t)row * 64);
    float4 qA[4], qB[4];
#pragma unroll
    for (int q = 0; q < 4; ++q) qA[q] = rp4[q];
#pragma unroll
    for (int kc = 0; kc < 4; ++kc) {
      const float* curq = (kc & 1) ? (const float*)qB : (const float*)qA;
      float4* nxt = (kc & 1) ? qA : qB;
      if (kc < 3) {
#pragma unroll
        for (int q = 0; q < 4; ++q) nxt[q] = rp4[(kc + 1) * 4 + q];
      }
#pragma unroll
      for (int kk = 0; kk < 16; ++kk) {
        float hk = curq[kk];
        const float* wr = wb + (kc * 16 + kk) * 36;  // uniform -> s_load
#pragma unroll
        for (int j = 0; j < 36; ++j) acc[j] = fmaf(hk, wr[j], acc[j]);
      }
    }
  }
  if (PASS == 1) {
    __shared__ float red[TT * 37];
    __shared__ float red2[252 * 2];
    if (act) {
#pragma unroll
      for (int j = 0; j < 36; ++j) red[tid * 37 + j] = acc[j];
    }
    __syncthreads();
    if (tid < 252) {
      int ch = tid / 7, seg = tid - ch * 7;
      int r0 = seg * 29, r1 = r0 + 29 < TT ? r0 + 29 : TT;
      float s1 = 0.f, s2 = 0.f;
      for (int r = r0; r < r1; ++r) {
        float v = red[r * 37 + ch];
        s1 += v;
        s2 += v * v;
      }
      red2[tid * 2] = s1;
      red2[tid * 2 + 1] = s2;
    }
    __syncthreads();
    if (tid < 36) {
      float s1 = 0.f, s2 = 0.f;
#pragma unroll
      for (int seg = 0; seg < 7; ++seg) {
        s1 += red2[(tid * 7 + seg) * 2];
        s2 += red2[(tid * 7 + seg) * 2 + 1];
      }
      PART[b * 72 + tid] = s1;
      PART[b * 72 + 36 + tid] = s2;
    }
  } else {
    if (act) {
      float w = auB2[0];
#pragma unroll
      for (int j = 0; j < 36; ++j) {
        float x = acc[j];
        float xh = (x - AUST[j]) * AUST[36 + j];
        float p = 1.0f / (1.0f + __expf(-xh));
        float a = auA1[j];
        w += x * (a + p * (1.0f - a)) * auW2[j];
      }
      Wbuf[b * TT + tid] = w;
    }
  }
}

// ---- AU stats finalize over per-b partials ----
__global__ __launch_bounds__(256) void k_aust(const float* __restrict__ PART,
                                              float* __restrict__ AUST) {
  int ch = blockIdx.x, tid = threadIdx.x;  // grid 36
  float s1 = 0.f, s2 = 0.f;
  for (int b = tid; b < BB; b += 256) {
    s1 += PART[b * 72 + ch];
    s2 += PART[b * 72 + 36 + ch];
  }
  __shared__ float r1[256], r2[256];
  r1[tid] = s1;
  r2[tid] = s2;
  __syncthreads();
  for (int off = 128; off > 0; off >>= 1) {
    if (tid < off) { r1[tid] += r1[tid + off]; r2[tid] += r2[tid + off]; }
    __syncthreads();
  }
  if (tid == 0) {
    float m = r1[0] / (float)NT;
    float var = r2[0] / (float)NT - m * m;
    AUST[ch] = m;
    AUST[36 + ch] = 1.0f / sqrtf(var + 1e-8f);
  }
}

// ---- pooling + x-concat + MLP layer1 ----
__global__ __launch_bounds__(256) void k_pool(
    const int* __restrict__ hist, const int* __restrict__ user,
    const int* __restrict__ item, const int* __restrict__ cate,
    const float* __restrict__ Itab, const float* __restrict__ Utab,
    const float* __restrict__ Ctab, const float* __restrict__ Wbuf,
    const float* __restrict__ W1, const float* __restrict__ b1,
    float* __restrict__ Y1) {
  int b = blockIdx.x, tid = threadIdx.x;
  __shared__ float sW[TT];
  __shared__ int sRows[TT];
  __shared__ float sPart[256];
  __shared__ float sX[256];
  if (tid < TT) {
    sW[tid] = Wbuf[b * TT + tid];
    sRows[tid] = hist[b * TT + tid];
  }
  __syncthreads();
  {
    int k = tid & 63, g = tid >> 6;
    float c = 0.f;
    int t0 = g * 50;
#pragma unroll 5
    for (int t = t0; t < t0 + 50; ++t)
      c += sW[t] * Itab[(size_t)sRows[t] * 64 + k];
    sPart[tid] = c;
  }
  __syncthreads();
  if (tid < 64) {
    float cur = sPart[tid] + sPart[64 + tid] + sPart[128 + tid] + sPart[192 + tid];
    sX[tid] = Utab[(size_t)user[b] * 64 + tid];
    sX[64 + tid] = Itab[(size_t)item[b] * 64 + tid];
    sX[128 + tid] = Ctab[(size_t)cate[b] * 64 + tid];
    sX[192 + tid] = cur;
  }
  __syncthreads();
  if (tid < 80) {
    float a = b1[tid];
    for (int k = 0; k < 256; ++k) a += sX[k] * W1[k * 80 + tid];
    Y1[b * 80 + tid] = a;
  }
}

// ---- per-channel batch stats over [B, nch] ----
__global__ __launch_bounds__(256) void k_colstats(const float* __restrict__ src,
                                                  int nch, float* __restrict__ st) {
  int ch = blockIdx.x, tid = threadIdx.x;
  float s1 = 0.f, s2 = 0.f;
  for (int r = tid; r < BB; r += 256) {
    float v = src[r * nch + ch];
    s1 += v;
    s2 += v * v;
  }
  __shared__ float r1[256], r2[256];
  r1[tid] = s1;
  r2[tid] = s2;
  __syncthreads();
  for (int off = 128; off > 0; off >>= 1) {
    if (tid < off) { r1[tid] += r1[tid + off]; r2[tid] += r2[tid + off]; }
    __syncthreads();
  }
  if (tid == 0) {
    float m = r1[0] / (float)BB;
    float var = r2[0] / (float)BB - m * m;
    st[ch] = m;
    st[nch + ch] = 1.0f / sqrtf(var + 1e-8f);
  }
}

// ---- MLP layer 2 ----
__global__ __launch_bounds__(128) void k_mlp2(const float* __restrict__ Y1,
                                              const float* __restrict__ ST80,
                                              const float* __restrict__ a1,
                                              const float* __restrict__ W2,
                                              const float* __restrict__ b2,
                                              float* __restrict__ Y2) {
  int b = blockIdx.x, tid = threadIdx.x;
  __shared__ float sY[80];
  if (tid < 80) {
    float x = Y1[b * 80 + tid];
    float xh = (x - ST80[tid]) * ST80[80 + tid];
    float p = 1.0f / (1.0f + expf(-xh));
    sY[tid] = p * x + (1.0f - p) * a1[tid] * x;
  }
  __syncthreads();
  if (tid < 40) {
    float a = b2[tid];
    for (int k = 0; k < 80; ++k) a += sY[k] * W2[k * 40 + tid];
    Y2[b * 40 + tid] = a;
  }
}

// ---- MLP layer 3 ----
__global__ __launch_bounds__(64) void k_mlp3(const float* __restrict__ Y2,
                                             const float* __restrict__ ST40,
                                             const float* __restrict__ a2,
                                             const float* __restrict__ W3,
                                             const float* __restrict__ b3,
                                             float* __restrict__ out) {
  int b = blockIdx.x, tid = threadIdx.x;
  __shared__ float sY[40];
  if (tid < 40) {
    float x = Y2[b * 40 + tid];
    float xh = (x - ST40[tid]) * ST40[40 + tid];
    float p = 1.0f / (1.0f + expf(-xh));
    sY[tid] = p * x + (1.0f - p) * a2[tid] * x;
  }
  __syncthreads();
  if (tid < 2) {
    float a = b3[tid];
    for (int k = 0; k < 40; ++k) a += sY[k] * W3[k * 2 + tid];
    out[b * 2 + tid] = a;
  }
}

extern "C" void kernel_launch(void* const* d_in, const int* in_sizes, int n_in,
                              void* d_out, int out_size, void* d_ws, size_t ws_size,
                              hipStream_t stream) {
  const int* user = (const int*)d_in[0];
  const int* hist = (const int*)d_in[1];
  const int* item = (const int*)d_in[2];
  const int* cate = (const int*)d_in[3];
  const float* Utab = (const float*)d_in[4];
  const float* Itab = (const float*)d_in[5];
  const float* Ctab = (const float*)d_in[6];
  const float* auW1 = (const float*)d_in[7];
  const float* auB1 = (const float*)d_in[8];
  const float* auA1 = (const float*)d_in[9];
  const float* auW2 = (const float*)d_in[10];
  const float* auB2 = (const float*)d_in[11];
  const float* W1 = (const float*)d_in[12];
  const float* b1 = (const float*)d_in[13];
  const float* a1 = (const float*)d_in[14];
  const float* W2 = (const float*)d_in[15];
  const float* b2 = (const float*)d_in[16];
  const float* a2 = (const float*)d_in[17];
  const float* W3 = (const float*)d_in[18];
  const float* b3 = (const float*)d_in[19];
  float* out = (float*)d_out;

  float* ws = (float*)d_ws;
  float* WBtab = ws;                     // BB*2304  (37.7 MB)
  float* TBuf = WBtab + (size_t)BB * 2304; // BB*36
  float* PART = TBuf + BB * 36;          // BB*72
  float* AUST = PART + BB * 72;          // 72
  float* Wbuf = AUST + 72;               // NT
  float* Y1 = Wbuf + NT;                 // BB*80
  float* ST80 = Y1 + BB * 80;            // 160
  float* Y2 = ST80 + 160;                // BB*40
  float* ST40 = Y2 + BB * 40;            // 80

  k_prep<<<BB, 256, 0, stream>>>(item, Itab, auW1, auB1, WBtab, TBuf);
  k_core_sg<1><<<BB, 256, 0, stream>>>(hist, Itab, WBtab, TBuf, nullptr,
                                       nullptr, nullptr, nullptr, PART, nullptr);
  k_aust<<<36, 256, 0, stream>>>(PART, AUST);
  k_core_sg<2><<<BB, 256, 0, stream>>>(hist, Itab, WBtab, TBuf, AUST, auA1,
                                       auW2, auB2, nullptr, Wbuf);
  k_pool<<<BB, 256, 0, stream>>>(hist, user, item, cate, Itab, Utab, Ctab,
                                 Wbuf, W1, b1, Y1);
  k_colstats<<<80, 256, 0, stream>>>(Y1, 80, ST80);
  k_mlp2<<<BB, 128, 0, stream>>>(Y1, ST80, a1, W2, b2, Y2);
  k_colstats<<<40, 256, 0, stream>>>(Y2, 40, ST40);
  k_mlp3<<<BB, 64, 0, stream>>>(Y2, ST40, a2, W3, b3, out);
}

// Round 4
// 353.078 us; speedup vs baseline: 1.0523x; 1.0523x over previous
//
#include <hip/hip_runtime.h>
#include <math.h>

#define BB 4096
#define TT 200
#define NT (BB*TT)
#define TC 100   // t-chunk per LDS stage (2 chunks of 100)

// ---- prep: WE = Wa + Wc ----
__global__ __launch_bounds__(256) void k_prep_we(const float* __restrict__ auW1,
                                                 float* __restrict__ WE) {
  int i = blockIdx.x * 256 + threadIdx.x;
  if (i < 64 * 36) WE[i] = auW1[i] + auW1[128 * 36 + i];
}

// ---- prep: TBuf[b][36] = ie_b @ (Wb - Wc) + au_b1 ----
__global__ __launch_bounds__(64) void k_prep_tb(const int* __restrict__ item,
                                                const float* __restrict__ Itab,
                                                const float* __restrict__ auW1,
                                                const float* __restrict__ auB1,
                                                float* __restrict__ TBuf) {
  int b = blockIdx.x, tid = threadIdx.x;
  __shared__ float sIe[64];
  sIe[tid] = Itab[(size_t)item[b] * 64 + tid];
  __syncthreads();
  if (tid < 36) {
    float a = auB1[tid];
    for (int k = 0; k < 64; ++k)
      a += sIe[k] * (auW1[(64 + k) * 36 + tid] - auW1[(128 + k) * 36 + tid]);
    TBuf[b * 36 + tid] = a;
  }
}

// ---- core: block = one b. wave wv owns j-columns [wv*9, wv*9+9).
// lane handles t = c0 + l and t = c0 + 64 + l (latter valid iff l < TC-64).
// PASS 1: per-b stats partials.  PASS 2: dice+w, fused pool + concat + MLP1.
template<int PASS>
__global__ __launch_bounds__(256, 3) void k_core2(
    const int* __restrict__ hist, const int* __restrict__ item,
    const int* __restrict__ user, const int* __restrict__ cate,
    const float* __restrict__ Itab, const float* __restrict__ Utab,
    const float* __restrict__ Ctab, const float* __restrict__ WE,
    const float* __restrict__ WD, const float* __restrict__ TBuf,
    const float* __restrict__ AUST, const float* __restrict__ auA1,
    const float* __restrict__ auW2, const float* __restrict__ auB2,
    const float* __restrict__ W1, const float* __restrict__ b1,
    float* __restrict__ PART, float* __restrict__ Y1) {
  const int b = blockIdx.x, tid = threadIdx.x;
  const int wv = tid >> 6, l = tid & 63;
  __shared__ float sWB[64 * 48];       // [k][wave][12] (9 used, aligned)
  __shared__ float sHe[TC * 65];       // stride 65: column reads conflict-free
  __shared__ float sIe[64];
  __shared__ float sTB[36];
  __shared__ float sWp[4][TC + 4];     // pass2: per-wave w partials
  __shared__ float sW[TC];             // pass2: combined attention weights
  __shared__ float sCur[256];          // pass2: pooling partials
  __shared__ float sX[256];            // pass2: concat vector

  if (tid < 64) sIe[tid] = Itab[(size_t)item[b] * 64 + tid];
  if (tid >= 64 && tid < 100) sTB[tid - 64] = TBuf[b * 36 + (tid - 64)];
  if (PASS == 2) sCur[tid] = 0.f;
  __syncthreads();
  // build per-b weights: WB[k][j] = WE[k][j] + ie[k]*WD[k][j], laid [k][w][12]
  for (int i = tid; i < 2304; i += 256) {
    int k = i / 36, j = i - k * 36;
    sWB[k * 48 + (j / 9) * 12 + (j % 9)] = WE[i] + sIe[k] * WD[i];
  }

  // pass-2 per-wave dice constants for its 9 channels
  float dmu[9], drs[9], dal[9], dw2[9];
  if (PASS == 2) {
#pragma unroll
    for (int jj = 0; jj < 9; ++jj) {
      int j = wv * 9 + jj;
      dmu[jj] = AUST[j];
      drs[jj] = AUST[36 + j];
      dal[jj] = auA1[j];
      dw2[jj] = auW2[j];
    }
  }

  float sSum[9], sSq[9];
#pragma unroll
  for (int jj = 0; jj < 9; ++jj) { sSum[jj] = 0.f; sSq[jj] = 0.f; }

  const bool v1 = (l < TC - 64);     // validity of second task slot
  const int t1l = v1 ? (l + 64) : l; // clamped (garbage discarded)

  for (int c0 = 0; c0 < TT; c0 += TC) {
    __syncthreads();   // sWB ready (c0==0) / previous-chunk sHe readers done
    // stage he chunk: 16 threads per row, 64B segments, coalesced per row
    for (int i = tid; i < TC * 16; i += 256) {
      int r = i >> 4, q = i & 15;
      int row = hist[b * TT + c0 + r];
      const float4 v = ((const float4*)(Itab + (size_t)row * 64))[q];
      float* d = sHe + r * 65 + q * 4;
      d[0] = v.x; d[1] = v.y; d[2] = v.z; d[3] = v.w;
    }
    __syncthreads();

    float acc[2][9];
#pragma unroll
    for (int m = 0; m < 2; ++m)
#pragma unroll
      for (int jj = 0; jj < 9; ++jj) acc[m][jj] = 0.f;

    const float* wbW = sWB + wv * 12;
#pragma unroll 4
    for (int k = 0; k < 64; ++k) {
      float h0 = sHe[l * 65 + k];
      float h1 = sHe[t1l * 65 + k];
      const float4* wp = (const float4*)(wbW + k * 48);
      float4 wa = wp[0], wb4 = wp[1];
      float w8 = wbW[k * 48 + 8];
      acc[0][0] = fmaf(h0, wa.x, acc[0][0]);
      acc[0][1] = fmaf(h0, wa.y, acc[0][1]);
      acc[0][2] = fmaf(h0, wa.z, acc[0][2]);
      acc[0][3] = fmaf(h0, wa.w, acc[0][3]);
      acc[0][4] = fmaf(h0, wb4.x, acc[0][4]);
      acc[0][5] = fmaf(h0, wb4.y, acc[0][5]);
      acc[0][6] = fmaf(h0, wb4.z, acc[0][6]);
      acc[0][7] = fmaf(h0, wb4.w, acc[0][7]);
      acc[0][8] = fmaf(h0, w8, acc[0][8]);
      acc[1][0] = fmaf(h1, wa.x, acc[1][0]);
      acc[1][1] = fmaf(h1, wa.y, acc[1][1]);
      acc[1][2] = fmaf(h1, wa.z, acc[1][2]);
      acc[1][3] = fmaf(h1, wa.w, acc[1][3]);
      acc[1][4] = fmaf(h1, wb4.x, acc[1][4]);
      acc[1][5] = fmaf(h1, wb4.y, acc[1][5]);
      acc[1][6] = fmaf(h1, wb4.z, acc[1][6]);
      acc[1][7] = fmaf(h1, wb4.w, acc[1][7]);
      acc[1][8] = fmaf(h1, w8, acc[1][8]);
    }
    // add tb (uniform per wave-channel)
#pragma unroll
    for (int jj = 0; jj < 9; ++jj) {
      float tb = sTB[wv * 9 + jj];
      acc[0][jj] += tb;
      acc[1][jj] += tb;
    }

    if (PASS == 1) {
#pragma unroll
      for (int jj = 0; jj < 9; ++jj) {
        float x0 = acc[0][jj];
        sSum[jj] += x0;
        sSq[jj] += x0 * x0;
        if (v1) {
          float x1 = acc[1][jj];
          sSum[jj] += x1;
          sSq[jj] += x1 * x1;
        }
      }
    } else {
      float pw0 = 0.f, pw1 = 0.f;
#pragma unroll
      for (int jj = 0; jj < 9; ++jj) {
        float x0 = acc[0][jj];
        float xh0 = (x0 - dmu[jj]) * drs[jj];
        float p0 = 1.0f / (1.0f + __expf(-xh0));
        pw0 = fmaf(x0 * (dal[jj] + p0 * (1.0f - dal[jj])), dw2[jj], pw0);
        float x1 = acc[1][jj];
        float xh1 = (x1 - dmu[jj]) * drs[jj];
        float p1 = 1.0f / (1.0f + __expf(-xh1));
        pw1 = fmaf(x1 * (dal[jj] + p1 * (1.0f - dal[jj])), dw2[jj], pw1);
      }
      sWp[wv][l] = pw0;
      if (v1) sWp[wv][64 + l] = pw1;
      __syncthreads();
      if (tid < TC)
        sW[tid] = auB2[0] + sWp[0][tid] + sWp[1][tid] + sWp[2][tid] + sWp[3][tid];
      __syncthreads();
      // pool this chunk: wave wv covers 25 rows, lane l = channel d
      {
        float c = sCur[tid];
        int t0 = wv * 25;
#pragma unroll 5
        for (int t = t0; t < t0 + 25; ++t)
          c = fmaf(sW[t], sHe[t * 65 + l], c);
        sCur[tid] = c;
      }
    }
  }

  if (PASS == 1) {
    // butterfly reduce across 64 lanes, then lane 0 writes
#pragma unroll
    for (int jj = 0; jj < 9; ++jj) {
      float s = sSum[jj], q = sSq[jj];
      for (int off = 1; off < 64; off <<= 1) {
        s += __shfl_xor(s, off, 64);
        q += __shfl_xor(q, off, 64);
      }
      if (l == 0) {
        PART[b * 72 + wv * 9 + jj] = s;
        PART[b * 72 + 36 + wv * 9 + jj] = q;
      }
    }
  } else {
    __syncthreads();
    if (tid < 64) {
      float cur = sCur[tid] + sCur[64 + tid] + sCur[128 + tid] + sCur[192 + tid];
      sX[tid] = Utab[(size_t)user[b] * 64 + tid];
      sX[64 + tid] = sIe[tid];
      sX[128 + tid] = Ctab[(size_t)cate[b] * 64 + tid];
      sX[192 + tid] = cur;
    }
    __syncthreads();
    if (tid < 80) {
      float a = b1[tid];
      for (int k = 0; k < 256; ++k) a = fmaf(sX[k], W1[k * 80 + tid], a);
      Y1[b * 80 + tid] = a;
    }
  }
}

// ---- AU stats finalize ----
__global__ __launch_bounds__(256) void k_aust(const float* __restrict__ PART,
                                              float* __restrict__ AUST) {
  int ch = blockIdx.x, tid = threadIdx.x;  // grid 36
  float s1 = 0.f, s2 = 0.f;
  for (int b = tid; b < BB; b += 256) {
    s1 += PART[b * 72 + ch];
    s2 += PART[b * 72 + 36 + ch];
  }
  __shared__ float r1[256], r2[256];
  r1[tid] = s1;
  r2[tid] = s2;
  __syncthreads();
  for (int off = 128; off > 0; off >>= 1) {
    if (tid < off) { r1[tid] += r1[tid + off]; r2[tid] += r2[tid + off]; }
    __syncthreads();
  }
  if (tid == 0) {
    float m = r1[0] / (float)NT;
    float var = r2[0] / (float)NT - m * m;
    AUST[ch] = m;
    AUST[36 + ch] = 1.0f / sqrtf(var + 1e-8f);
  }
}

// ---- per-channel batch stats over [B, nch] ----
__global__ __launch_bounds__(256) void k_colstats(const float* __restrict__ src,
                                                  int nch, float* __restrict__ st) {
  int ch = blockIdx.x, tid = threadIdx.x;
  float s1 = 0.f, s2 = 0.f;
  for (int r = tid; r < BB; r += 256) {
    float v = src[r * nch + ch];
    s1 += v;
    s2 += v * v;
  }
  __shared__ float r1[256], r2[256];
  r1[tid] = s1;
  r2[tid] = s2;
  __syncthreads();
  for (int off = 128; off > 0; off >>= 1) {
    if (tid < off) { r1[tid] += r1[tid + off]; r2[tid] += r2[tid + off]; }
    __syncthreads();
  }
  if (tid == 0) {
    float m = r1[0] / (float)BB;
    float var = r2[0] / (float)BB - m * m;
    st[ch] = m;
    st[nch + ch] = 1.0f / sqrtf(var + 1e-8f);
  }
}

// ---- MLP layer 2 ----
__global__ __launch_bounds__(128) void k_mlp2(const float* __restrict__ Y1,
                                              const float* __restrict__ ST80,
                                              const float* __restrict__ a1,
                                              const float* __restrict__ W2,
                                              const float* __restrict__ b2,
                                              float* __restrict__ Y2) {
  int b = blockIdx.x, tid = threadIdx.x;
  __shared__ float sY[80];
  if (tid < 80) {
    float x = Y1[b * 80 + tid];
    float xh = (x - ST80[tid]) * ST80[80 + tid];
    float p = 1.0f / (1.0f + expf(-xh));
    sY[tid] = p * x + (1.0f - p) * a1[tid] * x;
  }
  __syncthreads();
  if (tid < 40) {
    float a = b2[tid];
    for (int k = 0; k < 80; ++k) a += sY[k] * W2[k * 40 + tid];
    Y2[b * 40 + tid] = a;
  }
}

// ---- MLP layer 3 ----
__global__ __launch_bounds__(64) void k_mlp3(const float* __restrict__ Y2,
                                             const float* __restrict__ ST40,
                                             const float* __restrict__ a2,
                                             const float* __restrict__ W3,
                                             const float* __restrict__ b3,
                                             float* __restrict__ out) {
  int b = blockIdx.x, tid = threadIdx.x;
  __shared__ float sY[40];
  if (tid < 40) {
    float x = Y2[b * 40 + tid];
    float xh = (x - ST40[tid]) * ST40[40 + tid];
    float p = 1.0f / (1.0f + expf(-xh));
    sY[tid] = p * x + (1.0f - p) * a2[tid] * x;
  }
  __syncthreads();
  if (tid < 2) {
    float a = b3[tid];
    for (int k = 0; k < 40; ++k) a += sY[k] * W3[k * 2 + tid];
    out[b * 2 + tid] = a;
  }
}

extern "C" void kernel_launch(void* const* d_in, const int* in_sizes, int n_in,
                              void* d_out, int out_size, void* d_ws, size_t ws_size,
                              hipStream_t stream) {
  const int* user = (const int*)d_in[0];
  const int* hist = (const int*)d_in[1];
  const int* item = (const int*)d_in[2];
  const int* cate = (const int*)d_in[3];
  const float* Utab = (const float*)d_in[4];
  const float* Itab = (const float*)d_in[5];
  const float* Ctab = (const float*)d_in[6];
  const float* auW1 = (const float*)d_in[7];
  const float* auB1 = (const float*)d_in[8];
  const float* auA1 = (const float*)d_in[9];
  const float* auW2 = (const float*)d_in[10];
  const float* auB2 = (const float*)d_in[11];
  const float* W1 = (const float*)d_in[12];
  const float* b1 = (const float*)d_in[13];
  const float* a1 = (const float*)d_in[14];
  const float* W2 = (const float*)d_in[15];
  const float* b2 = (const float*)d_in[16];
  const float* a2 = (const float*)d_in[17];
  const float* W3 = (const float*)d_in[18];
  const float* b3 = (const float*)d_in[19];
  float* out = (float*)d_out;

  float* ws = (float*)d_ws;
  float* WE = ws;                         // 2304
  float* TBuf = WE + 2304;                // BB*36
  float* PART = TBuf + BB * 36;           // BB*72
  float* AUST = PART + BB * 72;           // 72
  float* Y1 = AUST + 72;                  // BB*80
  float* ST80 = Y1 + BB * 80;             // 160
  float* Y2 = ST80 + 160;                 // BB*40
  float* ST40 = Y2 + BB * 40;             // 80

  const float* WD = auW1 + 192 * 36;

  k_prep_we<<<9, 256, 0, stream>>>(auW1, WE);
  k_prep_tb<<<BB, 64, 0, stream>>>(item, Itab, auW1, auB1, TBuf);
  k_core2<1><<<BB, 256, 0, stream>>>(hist, item, user, cate, Itab, Utab, Ctab,
                                     WE, WD, TBuf, nullptr, nullptr, nullptr,
                                     nullptr, nullptr, nullptr, PART, nullptr);
  k_aust<<<36, 256, 0, stream>>>(PART, AUST);
  k_core2<2><<<BB, 256, 0, stream>>>(hist, item, user, cate, Itab, Utab, Ctab,
                                     WE, WD, TBuf, AUST, auA1, auW2, auB2,
                                     W1, b1, nullptr, Y1);
  k_colstats<<<80, 256, 0, stream>>>(Y1, 80, ST80);
  k_mlp2<<<BB, 128, 0, stream>>>(Y1, ST80, a1, W2, b2, Y2);
  k_colstats<<<40, 256, 0, stream>>>(Y2, 40, ST40);
  k_mlp3<<<BB, 64, 0, stream>>>(Y2, ST40, a2, W3, b3, out);
}

// Round 5
// 275.798 us; speedup vs baseline: 1.3471x; 1.2802x over previous
//
#include <hip/hip_runtime.h>
#include <math.h>

#define BB 4096
#define TT 200
#define NT (BB*TT)

// ---- prep: WE = Wa + Wc ----
__global__ __launch_bounds__(256) void k_prep_we(const float* __restrict__ auW1,
                                                 float* __restrict__ WE) {
  int i = blockIdx.x * 256 + threadIdx.x;
  if (i < 64 * 36) WE[i] = auW1[i] + auW1[128 * 36 + i];
}

// ---- prep: TBuf[b][36] = ie_b @ (Wb - Wc) + au_b1 ----
__global__ __launch_bounds__(64) void k_prep_tb(const int* __restrict__ item,
                                                const float* __restrict__ Itab,
                                                const float* __restrict__ auW1,
                                                const float* __restrict__ auB1,
                                                float* __restrict__ TBuf) {
  int b = blockIdx.x, tid = threadIdx.x;
  __shared__ float sIe[64];
  sIe[tid] = Itab[(size_t)item[b] * 64 + tid];
  __syncthreads();
  if (tid < 36) {
    float a = auB1[tid];
    for (int k = 0; k < 64; ++k)
      a += sIe[k] * (auW1[(64 + k) * 36 + tid] - auW1[(128 + k) * 36 + tid]);
    TBuf[b * 36 + tid] = a;
  }
}

// ---- core: block = one b, lane = one t (t = tid, active if < 200).
// he streamed from global float4; per-b weights in LDS, uniform b128 reads.
// PASS 1: per-b stats partials.  PASS 2: dice + w + fused pool/concat/MLP1.
template<int PASS>
__global__ __launch_bounds__(256, 4) void k_core3(
    const int* __restrict__ hist, const int* __restrict__ item,
    const int* __restrict__ user, const int* __restrict__ cate,
    const float* __restrict__ Itab, const float* __restrict__ Utab,
    const float* __restrict__ Ctab, const float* __restrict__ WE,
    const float* __restrict__ WD, const float* __restrict__ TBuf,
    const float* __restrict__ AUST, const float* __restrict__ auA1,
    const float* __restrict__ auW2, const float* __restrict__ auB2,
    const float* __restrict__ W1, const float* __restrict__ b1,
    float* __restrict__ PART, float* __restrict__ Y1) {
  const int b = blockIdx.x, tid = threadIdx.x;
  __shared__ float sWB[2304];                         // [k][36]
  __shared__ float sIe[64];
  __shared__ float sTB[36];
  __shared__ float red[(PASS == 1) ? (TT * 37) : 1];  // pass1 stats buffer
  __shared__ float red2[(PASS == 1) ? (252 * 2) : 1];
  __shared__ float sW[(PASS == 2) ? TT : 1];
  __shared__ float sPart[(PASS == 2) ? 256 : 1];
  __shared__ float sX[(PASS == 2) ? 256 : 1];

  if (tid < 64) sIe[tid] = Itab[(size_t)item[b] * 64 + tid];
  if (tid >= 64 && tid < 100) sTB[tid - 64] = TBuf[b * 36 + (tid - 64)];
  __syncthreads();
  for (int i = tid; i < 2304; i += 256) {
    int k = i / 36;
    sWB[i] = WE[i] + sIe[k] * WD[i];
  }
  __syncthreads();

  const bool act = tid < TT;
  const int t = act ? tid : (TT - 1);
  const int row = hist[b * TT + t];
  const float4* __restrict__ rp4 = (const float4*)(Itab + (size_t)row * 64);

  float acc[36];
#pragma unroll
  for (int j = 0; j < 36; ++j) acc[j] = sTB[j];

  for (int kc = 0; kc < 4; ++kc) {       // rolled: small I-footprint
    float4 q0 = rp4[kc * 4 + 0];
    float4 q1 = rp4[kc * 4 + 1];
    float4 q2 = rp4[kc * 4 + 2];
    float4 q3 = rp4[kc * 4 + 3];
    const float he16[16] = {q0.x, q0.y, q0.z, q0.w, q1.x, q1.y, q1.z, q1.w,
                            q2.x, q2.y, q2.z, q2.w, q3.x, q3.y, q3.z, q3.w};
    const float* wbase = sWB + kc * 16 * 36;
#pragma unroll
    for (int kk = 0; kk < 16; ++kk) {
      float hk = he16[kk];
      const float4* wp = (const float4*)(wbase + kk * 36);
#pragma unroll
      for (int jg = 0; jg < 9; ++jg) {
        float4 wv = wp[jg];
        acc[jg * 4 + 0] = fmaf(hk, wv.x, acc[jg * 4 + 0]);
        acc[jg * 4 + 1] = fmaf(hk, wv.y, acc[jg * 4 + 1]);
        acc[jg * 4 + 2] = fmaf(hk, wv.z, acc[jg * 4 + 2]);
        acc[jg * 4 + 3] = fmaf(hk, wv.w, acc[jg * 4 + 3]);
      }
    }
  }

  if (PASS == 1) {
    if (act) {
#pragma unroll
      for (int j = 0; j < 36; ++j) red[t * 37 + j] = acc[j];
    }
    __syncthreads();
    if (tid < 252) {
      int ch = tid / 7, seg = tid - ch * 7;
      int r0 = seg * 29, r1 = r0 + 29 < TT ? r0 + 29 : TT;
      float s1 = 0.f, s2 = 0.f;
      for (int r = r0; r < r1; ++r) {
        float v = red[r * 37 + ch];
        s1 += v;
        s2 += v * v;
      }
      red2[tid * 2] = s1;
      red2[tid * 2 + 1] = s2;
    }
    __syncthreads();
    if (tid < 36) {
      float s1 = 0.f, s2 = 0.f;
#pragma unroll
      for (int seg = 0; seg < 7; ++seg) {
        s1 += red2[(tid * 7 + seg) * 2];
        s2 += red2[(tid * 7 + seg) * 2 + 1];
      }
      PART[b * 72 + tid] = s1;
      PART[b * 72 + 36 + tid] = s2;
    }
  } else {
    // dice + attention weight (per-lane, uniform scalar constants)
    float w = auB2[0];
#pragma unroll
    for (int j = 0; j < 36; ++j) {
      float x = acc[j];
      float xh = (x - AUST[j]) * AUST[36 + j];
      float p = 1.0f / (1.0f + __expf(-xh));
      float a = auA1[j];
      w = fmaf(x * (a + p * (1.0f - a)), auW2[j], w);
    }
    if (act) sW[t] = w;
    __syncthreads();
    // pool: wave wv covers t in [wv*50, wv*50+50); lane l = channel d
    {
      const int l = tid & 63, wv = tid >> 6;
      const int* hp = hist + b * TT;
      float c = 0.f;
      int t0 = wv * 50;
      for (int u = t0; u < t0 + 50; ++u) {
        int r = hp[u];                                  // wave-uniform
        c = fmaf(sW[u], Itab[(size_t)r * 64 + l], c);   // coalesced 256B
      }
      sPart[tid] = c;
    }
    __syncthreads();
    if (tid < 64) {
      float cur = sPart[tid] + sPart[64 + tid] + sPart[128 + tid] + sPart[192 + tid];
      sX[tid] = Utab[(size_t)user[b] * 64 + tid];
      sX[64 + tid] = sIe[tid];
      sX[128 + tid] = Ctab[(size_t)cate[b] * 64 + tid];
      sX[192 + tid] = cur;
    }
    __syncthreads();
    if (tid < 80) {
      float a = b1[tid];
      for (int k = 0; k < 256; ++k) a = fmaf(sX[k], W1[k * 80 + tid], a);
      Y1[b * 80 + tid] = a;
    }
  }
}

// ---- AU stats finalize ----
__global__ __launch_bounds__(256) void k_aust(const float* __restrict__ PART,
                                              float* __restrict__ AUST) {
  int ch = blockIdx.x, tid = threadIdx.x;  // grid 36
  float s1 = 0.f, s2 = 0.f;
  for (int b = tid; b < BB; b += 256) {
    s1 += PART[b * 72 + ch];
    s2 += PART[b * 72 + 36 + ch];
  }
  __shared__ float r1[256], r2[256];
  r1[tid] = s1;
  r2[tid] = s2;
  __syncthreads();
  for (int off = 128; off > 0; off >>= 1) {
    if (tid < off) { r1[tid] += r1[tid + off]; r2[tid] += r2[tid + off]; }
    __syncthreads();
  }
  if (tid == 0) {
    float m = r1[0] / (float)NT;
    float var = r2[0] / (float)NT - m * m;
    AUST[ch] = m;
    AUST[36 + ch] = 1.0f / sqrtf(var + 1e-8f);
  }
}

// ---- per-channel batch stats over [B, nch] ----
__global__ __launch_bounds__(256) void k_colstats(const float* __restrict__ src,
                                                  int nch, float* __restrict__ st) {
  int ch = blockIdx.x, tid = threadIdx.x;
  float s1 = 0.f, s2 = 0.f;
  for (int r = tid; r < BB; r += 256) {
    float v = src[r * nch + ch];
    s1 += v;
    s2 += v * v;
  }
  __shared__ float r1[256], r2[256];
  r1[tid] = s1;
  r2[tid] = s2;
  __syncthreads();
  for (int off = 128; off > 0; off >>= 1) {
    if (tid < off) { r1[tid] += r1[tid + off]; r2[tid] += r2[tid + off]; }
    __syncthreads();
  }
  if (tid == 0) {
    float m = r1[0] / (float)BB;
    float var = r2[0] / (float)BB - m * m;
    st[ch] = m;
    st[nch + ch] = 1.0f / sqrtf(var + 1e-8f);
  }
}

// ---- MLP layer 2 ----
__global__ __launch_bounds__(128) void k_mlp2(const float* __restrict__ Y1,
                                              const float* __restrict__ ST80,
                                              const float* __restrict__ a1,
                                              const float* __restrict__ W2,
                                              const float* __restrict__ b2,
                                              float* __restrict__ Y2) {
  int b = blockIdx.x, tid = threadIdx.x;
  __shared__ float sY[80];
  if (tid < 80) {
    float x = Y1[b * 80 + tid];
    float xh = (x - ST80[tid]) * ST80[80 + tid];
    float p = 1.0f / (1.0f + expf(-xh));
    sY[tid] = p * x + (1.0f - p) * a1[tid] * x;
  }
  __syncthreads();
  if (tid < 40) {
    float a = b2[tid];
    for (int k = 0; k < 80; ++k) a += sY[k] * W2[k * 40 + tid];
    Y2[b * 40 + tid] = a;
  }
}

// ---- MLP layer 3 ----
__global__ __launch_bounds__(64) void k_mlp3(const float* __restrict__ Y2,
                                             const float* __restrict__ ST40,
                                             const float* __restrict__ a2,
                                             const float* __restrict__ W3,
                                             const float* __restrict__ b3,
                                             float* __restrict__ out) {
  int b = blockIdx.x, tid = threadIdx.x;
  __shared__ float sY[40];
  if (tid < 40) {
    float x = Y2[b * 40 + tid];
    float xh = (x - ST40[tid]) * ST40[40 + tid];
    float p = 1.0f / (1.0f + expf(-xh));
    sY[tid] = p * x + (1.0f - p) * a2[tid] * x;
  }
  __syncthreads();
  if (tid < 2) {
    float a = b3[tid];
    for (int k = 0; k < 40; ++k) a += sY[k] * W3[k * 2 + tid];
    out[b * 2 + tid] = a;
  }
}

extern "C" void kernel_launch(void* const* d_in, const int* in_sizes, int n_in,
                              void* d_out, int out_size, void* d_ws, size_t ws_size,
                              hipStream_t stream) {
  const int* user = (const int*)d_in[0];
  const int* hist = (const int*)d_in[1];
  const int* item = (const int*)d_in[2];
  const int* cate = (const int*)d_in[3];
  const float* Utab = (const float*)d_in[4];
  const float* Itab = (const float*)d_in[5];
  const float* Ctab = (const float*)d_in[6];
  const float* auW1 = (const float*)d_in[7];
  const float* auB1 = (const float*)d_in[8];
  const float* auA1 = (const float*)d_in[9];
  const float* auW2 = (const float*)d_in[10];
  const float* auB2 = (const float*)d_in[11];
  const float* W1 = (const float*)d_in[12];
  const float* b1 = (const float*)d_in[13];
  const float* a1 = (const float*)d_in[14];
  const float* W2 = (const float*)d_in[15];
  const float* b2 = (const float*)d_in[16];
  const float* a2 = (const float*)d_in[17];
  const float* W3 = (const float*)d_in[18];
  const float* b3 = (const float*)d_in[19];
  float* out = (float*)d_out;

  float* ws = (float*)d_ws;
  float* WE = ws;                         // 2304
  float* TBuf = WE + 2304;                // BB*36
  float* PART = TBuf + BB * 36;           // BB*72
  float* AUST = PART + BB * 72;           // 72
  float* Y1 = AUST + 72;                  // BB*80
  float* ST80 = Y1 + BB * 80;             // 160
  float* Y2 = ST80 + 160;                 // BB*40
  float* ST40 = Y2 + BB * 40;             // 80

  const float* WD = auW1 + 192 * 36;

  k_prep_we<<<9, 256, 0, stream>>>(auW1, WE);
  k_prep_tb<<<BB, 64, 0, stream>>>(item, Itab, auW1, auB1, TBuf);
  k_core3<1><<<BB, 256, 0, stream>>>(hist, item, user, cate, Itab, Utab, Ctab,
                                     WE, WD, TBuf, nullptr, nullptr, nullptr,
                                     nullptr, nullptr, nullptr, PART, nullptr);
  k_aust<<<36, 256, 0, stream>>>(PART, AUST);
  k_core3<2><<<BB, 256, 0, stream>>>(hist, item, user, cate, Itab, Utab, Ctab,
                                     WE, WD, TBuf, AUST, auA1, auW2, auB2,
                                     W1, b1, nullptr, Y1);
  k_colstats<<<80, 256, 0, stream>>>(Y1, 80, ST80);
  k_mlp2<<<BB, 128, 0, stream>>>(Y1, ST80, a1, W2, b2, Y2);
  k_colstats<<<40, 256, 0, stream>>>(Y2, 40, ST40);
  k_mlp3<<<BB, 64, 0, stream>>>(Y2, ST40, a2, W3, b3, out);
}